// Round 1
// baseline (404.130 us; speedup 1.0000x reference)
//
#include <hip/hip_runtime.h>
#include <hip/hip_bf16.h>

#define D_DIM 512
#define NROWS 256
#define NT 64
#define KSTEPS 16
#define S_SCALE 64.0f
#define COS_M 0.9210609940028851f
#define SIN_M 0.3894183423086505f

typedef short short8 __attribute__((ext_vector_type(8)));
typedef float f32x4 __attribute__((ext_vector_type(4)));

static __device__ __forceinline__ short f2bf(float f){
  __hip_bfloat16 h = __float2bfloat16(f);
  return __builtin_bit_cast(short, h);
}

// ---- emb = l2norm(x, 1e-5); also pack A-fragments (bf16, fragment-major) ----
__global__ void k_emb(const float* __restrict__ x, float* __restrict__ emb,
                      short* __restrict__ embA){
  int b = blockIdx.x, t = threadIdx.x;            // 256 blocks x 256 threads
  float v0 = x[b*D_DIM + t];
  float v1 = x[b*D_DIM + 256 + t];
  __shared__ float red[256];
  red[t] = v0*v0 + v1*v1;
  __syncthreads();
  for (int o=128;o>0;o>>=1){ if(t<o) red[t]+=red[t+o]; __syncthreads(); }
  float inv = 1.0f / fmaxf(sqrtf(red[0]), 1e-5f);
  float e0 = v0*inv, e1 = v1*inv;
  emb[b*D_DIM + t]       = e0;
  emb[b*D_DIM + 256 + t] = e1;
  // A-frag layout: lane l of rowblock rb holds A[row=l&15][k=(l>>4)*8+j]
  int rb = b >> 4;
  {
    int d=t; int ks=d>>5, kg=(d>>3)&3, j=d&7;
    int lane=(kg<<4)|(b&15);
    embA[((ks*16+rb)*64+lane)*8+j] = f2bf(e0);
  }
  {
    int d=t+256; int ks=d>>5, kg=(d>>3)&3, j=d&7;
    int lane=(kg<<4)|(b&15);
    embA[((ks*16+rb)*64+lane)*8+j] = f2bf(e1);
  }
}

__global__ void k_init(int* __restrict__ upd, int C){
  int i = blockIdx.x*256 + threadIdx.x;
  if (i < C) upd[i] = -1;
}

// ---- virtual-prototype update: newrow[b] = l2norm(f*q + (1-f)*emb, 1e-12) ----
// winner mask implements "last write wins" for duplicate labels.
__global__ void k_vp(const float* __restrict__ queue, const float* __restrict__ emb,
                     const int* __restrict__ labels, float* __restrict__ newrow,
                     int* __restrict__ upd){
  int b = blockIdx.x, t = threadIdx.x;            // 256 blocks x 256 threads
  int lab = labels[b];
  const float* q = queue + (size_t)lab * D_DIM;
  float q0=q[t], q1=q[t+256];
  float e0=emb[b*D_DIM+t], e1=emb[b*D_DIM+256+t];
  __shared__ float red[256];
  __shared__ int win;
  red[t] = q0*e0 + q1*e1;
  __syncthreads();
  for (int o=128;o>0;o>>=1){ if(t<o) red[t]+=red[t+o]; __syncthreads(); }
  float drift = red[0];
  float fac = drift / (1.0f + fabsf(drift));
  float v0 = fac*q0 + (1.0f-fac)*e0;
  float v1 = fac*q1 + (1.0f-fac)*e1;
  __syncthreads();
  if (t==0) win = 1;
  red[t] = v0*v0 + v1*v1;
  __syncthreads();
  for (int o=128;o>0;o>>=1){ if(t<o) red[t]+=red[t+o]; __syncthreads(); }
  float inv = 1.0f / fmaxf(sqrtf(red[0]), 1e-12f);
  newrow[b*D_DIM+t]     = v0*inv;
  newrow[b*D_DIM+256+t] = v1*inv;
  if (t > b && labels[t] == lab) win = 0;   // a later row owns this label
  __syncthreads();
  if (t==0 && win) upd[lab] = b;
}

// ---- fused double-GEMM + norms + margin + exp + row partial sums ----
// grid: ceil(C/64) wgs; 4 waves; wave w owns emb rows [w*64, w*64+64) x 64 cols x 2 mats
__global__ __launch_bounds__(256) void k_main(
    const float* __restrict__ W, const float* __restrict__ Q,
    const short* __restrict__ embA, const float* __restrict__ newrow,
    const int* __restrict__ upd, const int* __restrict__ labels,
    float* __restrict__ partials, float* __restrict__ posval,
    int C, int nwg)
{
  const int wg   = blockIdx.x;
  const int tid  = threadIdx.x;
  const int wave = tid >> 6;
  const int lane = tid & 63;
  const int lcol = lane & 15;
  const int lkg  = lane >> 4;
  const int c0 = wg * NT;
  const int m0 = wave * 64;

  const f32x4 vzero = {0.f,0.f,0.f,0.f};
  f32x4 accW[4][4], accQ[4][4];         // [rowblock][colblock]
#pragma unroll
  for (int i=0;i<4;i++)
#pragma unroll
    for (int j=0;j<4;j++){ accW[i][j]=vzero; accQ[i][j]=vzero; }

  float wss[4] = {0.f,0.f,0.f,0.f};
  float qss[4] = {0.f,0.f,0.f,0.f};

  const float* wp[4];
  const float* qp[4];
  bool valid[4];
#pragma unroll
  for (int cb=0;cb<4;cb++){
    int c = c0 + cb*16 + lcol;
    valid[cb] = (c < C);
    int ce = valid[cb] ? c : 0;
    wp[cb] = W + (size_t)ce * D_DIM;
    int u = valid[cb] ? upd[c] : -1;
    qp[cb] = (u >= 0) ? (newrow + (size_t)u * D_DIM) : (Q + (size_t)ce * D_DIM);
  }

  const short8* Af = reinterpret_cast<const short8*>(embA);

  for (int ks=0; ks<KSTEPS; ++ks){
    const int kof = ks*32 + lkg*8;
    short8 af[4];
#pragma unroll
    for (int rb=0;rb<4;rb++)
      af[rb] = Af[(ks*16 + wave*4 + rb)*64 + lane];
#pragma unroll
    for (int cb=0;cb<4;cb++){
      f32x4 w0=vzero, w1=vzero, z0=vzero, z1=vzero;
      if (valid[cb]){
        w0 = *reinterpret_cast<const f32x4*>(wp[cb] + kof);
        w1 = *reinterpret_cast<const f32x4*>(wp[cb] + kof + 4);
        z0 = *reinterpret_cast<const f32x4*>(qp[cb] + kof);
        z1 = *reinterpret_cast<const f32x4*>(qp[cb] + kof + 4);
      }
      wss[cb] += w0[0]*w0[0]+w0[1]*w0[1]+w0[2]*w0[2]+w0[3]*w0[3]
               + w1[0]*w1[0]+w1[1]*w1[1]+w1[2]*w1[2]+w1[3]*w1[3];
      qss[cb] += z0[0]*z0[0]+z0[1]*z0[1]+z0[2]*z0[2]+z0[3]*z0[3]
               + z1[0]*z1[0]+z1[1]*z1[1]+z1[2]*z1[2]+z1[3]*z1[3];
      short8 bw, bq;
#pragma unroll
      for (int j=0;j<4;j++){
        bw[j] = f2bf(w0[j]); bw[j+4] = f2bf(w1[j]);
        bq[j] = f2bf(z0[j]); bq[j+4] = f2bf(z1[j]);
      }
#pragma unroll
      for (int rb=0;rb<4;rb++)
        accW[rb][cb] = __builtin_amdgcn_mfma_f32_16x16x32_bf16(af[rb], bw, accW[rb][cb], 0, 0, 0);
#pragma unroll
      for (int rb=0;rb<4;rb++)
        accQ[rb][cb] = __builtin_amdgcn_mfma_f32_16x16x32_bf16(af[rb], bq, accQ[rb][cb], 0, 0, 0);
    }
  }

  // column norms: reduce sumsq across the 4 k-groups holding each column
  float winv[4], qinv[4];
#pragma unroll
  for (int cb=0;cb<4;cb++){
    float w = wss[cb]; w += __shfl_xor(w, 16); w += __shfl_xor(w, 32);
    float q = qss[cb]; q += __shfl_xor(q, 16); q += __shfl_xor(q, 32);
    winv[cb] = 1.0f / fmaxf(sqrtf(w), 1e-5f);
    qinv[cb] = 1.0f / fmaxf(sqrtf(q), 1e-12f);
  }

  // epilogue: clip, margin at label column, exp, per-row 16-lane reduce
#pragma unroll
  for (int rb=0;rb<4;rb++){
#pragma unroll
    for (int r=0;r<4;r++){
      const int m = m0 + rb*16 + lkg*4 + r;       // C/D row mapping
      const int lab = labels[m];
      float nw = 0.f, nq = 0.f;
#pragma unroll
      for (int cb=0;cb<4;cb++){
        int c = c0 + cb*16 + lcol;
        if (c < C){
          float cw = accW[rb][cb][r] * winv[cb];
          cw = fminf(fmaxf(cw, -1.0f + 1e-7f), 1.0f - 1e-7f);
          float cq = accQ[rb][cb][r] * qinv[cb];
          if (c == lab){
            float sw  = sqrtf(fminf(fmaxf(1.0f - cw*cw, 0.0f), 1.0f));
            float phw = cw*COS_M - sw*SIN_M;
            posval[m] = __expf(-S_SCALE*phw);
            float vq  = 0.3f * cq;                 // (1-K)*diag
            float sq  = sqrtf(fminf(fmaxf(1.0f - vq*vq, 0.0f), 1.0f));
            float phq = vq*COS_M - sq*SIN_M;
            posval[NROWS + m] = __expf(-S_SCALE*phq);
          } else {
            nw += __expf(S_SCALE*cw);
            nq += __expf(S_SCALE*cq);
          }
        }
      }
#pragma unroll
      for (int msk=1; msk<16; msk<<=1){
        nw += __shfl_xor(nw, msk);
        nq += __shfl_xor(nq, msk);
      }
      if (lcol == 0){
        partials[(size_t)m*nwg + wg]         = nw;
        partials[(size_t)(NROWS+m)*nwg + wg] = nq;
      }
    }
  }
}

// ---- reduce partials per row, loss per row ----
__global__ void k_red(const float* __restrict__ partials, const float* __restrict__ posval,
                      float* __restrict__ lossv, int nwg){
  int n = blockIdx.x, t = threadIdx.x;            // 512 blocks x 256 threads
  float s = 0.f;
  for (int i=t; i<nwg; i+=256) s += partials[(size_t)n*nwg + i];
  __shared__ float red[256];
  red[t] = s; __syncthreads();
  for (int o=128;o>0;o>>=1){ if(t<o) red[t]+=red[t+o]; __syncthreads(); }
  if (t==0) lossv[n] = logf(1.0f + red[0] * posval[n]);
}

__global__ void k_fin(const float* __restrict__ lossv, const int* __restrict__ epoch,
                      float* __restrict__ out){
  int t = threadIdx.x;                            // 1 block x 512 threads
  int N = (epoch[0] + 1 >= 4) ? 2*NROWS : NROWS;
  float v = (t < N) ? lossv[t] : 0.f;
  __shared__ float red[512];
  red[t] = v; __syncthreads();
  for (int o=256;o>0;o>>=1){ if(t<o) red[t]+=red[t+o]; __syncthreads(); }
  if (t==0) out[0] = red[0] / (float)N;
}

extern "C" void kernel_launch(void* const* d_in, const int* in_sizes, int n_in,
                              void* d_out, int out_size, void* d_ws, size_t ws_size,
                              hipStream_t stream)
{
  const float* x      = (const float*)d_in[0];
  const int*   labels = (const int*)d_in[1];
  const float* W      = (const float*)d_in[2];
  const float* Q      = (const float*)d_in[3];
  const int*   epoch  = (const int*)d_in[4];
  float* out = (float*)d_out;
  const int C   = in_sizes[2] / D_DIM;            // 100000
  const int nwg = (C + NT - 1) / NT;

  char* ws = (char*)d_ws;
  float* emb      = (float*)(ws + 0);             // 512 KB
  short* embA     = (short*)(ws + 524288);        // 256 KB
  float* newrow   = (float*)(ws + 786432);        // 512 KB
  int*   upd      = (int*)  (ws + 1310720);       // 400 KB
  float* posval   = (float*)(ws + 1712128);       // 2 KB
  float* lossv    = (float*)(ws + 1714176);       // 2 KB
  float* partials = (float*)(ws + 1716224);       // 512*nwg*4 B (~3.2 MB)

  hipLaunchKernelGGL(k_emb,  dim3(NROWS),       dim3(256), 0, stream, x, emb, embA);
  hipLaunchKernelGGL(k_init, dim3((C+255)/256), dim3(256), 0, stream, upd, C);
  hipLaunchKernelGGL(k_vp,   dim3(NROWS),       dim3(256), 0, stream, Q, emb, labels, newrow, upd);
  hipLaunchKernelGGL(k_main, dim3(nwg),         dim3(256), 0, stream,
                     W, Q, embA, newrow, upd, labels, partials, posval, C, nwg);
  hipLaunchKernelGGL(k_red,  dim3(2*NROWS),     dim3(256), 0, stream, partials, posval, lossv, nwg);
  hipLaunchKernelGGL(k_fin,  dim3(1),           dim3(512), 0, stream, lossv, epoch, out);
}

// Round 2
// 176.443 us; speedup vs baseline: 2.2904x; 2.2904x over previous
//
#include <hip/hip_runtime.h>
#include <hip/hip_bf16.h>

#define D_DIM 512
#define NROWS 256
#define NT 32
#define KSTEPS 16
#define S_SCALE 64.0f
#define COS_M 0.9210609940028851f
#define SIN_M 0.3894183423086505f

typedef short short8 __attribute__((ext_vector_type(8)));
typedef float f32x4 __attribute__((ext_vector_type(4)));

typedef const __attribute__((address_space(1))) void* gas1_t;
typedef __attribute__((address_space(3))) void* las3_t;

static __device__ __forceinline__ void gload16(const void* g, void* l){
  __builtin_amdgcn_global_load_lds((gas1_t)g, (las3_t)l, 16, 0, 0);
}

static __device__ __forceinline__ short f2bf(float f){
  __hip_bfloat16 h = __float2bfloat16(f);
  return __builtin_bit_cast(short, h);
}

// ---- emb = l2norm(x, 1e-5); also pack A-fragments (bf16, fragment-major) ----
__global__ void k_emb(const float* __restrict__ x, float* __restrict__ emb,
                      short* __restrict__ embA){
  int b = blockIdx.x, t = threadIdx.x;            // 256 blocks x 256 threads
  float v0 = x[b*D_DIM + t];
  float v1 = x[b*D_DIM + 256 + t];
  __shared__ float red[256];
  red[t] = v0*v0 + v1*v1;
  __syncthreads();
  for (int o=128;o>0;o>>=1){ if(t<o) red[t]+=red[t+o]; __syncthreads(); }
  float inv = 1.0f / fmaxf(sqrtf(red[0]), 1e-5f);
  float e0 = v0*inv, e1 = v1*inv;
  emb[b*D_DIM + t]       = e0;
  emb[b*D_DIM + 256 + t] = e1;
  // A-frag layout: lane l of rowblock rb holds A[row=l&15][k=(l>>4)*8+j]
  int rb = b >> 4;
  {
    int d=t; int ks=d>>5, kg=(d>>3)&3, j=d&7;
    int lane=(kg<<4)|(b&15);
    embA[((ks*16+rb)*64+lane)*8+j] = f2bf(e0);
  }
  {
    int d=t+256; int ks=d>>5, kg=(d>>3)&3, j=d&7;
    int lane=(kg<<4)|(b&15);
    embA[((ks*16+rb)*64+lane)*8+j] = f2bf(e1);
  }
}

__global__ void k_init(int* __restrict__ upd, int C){
  int i = blockIdx.x*256 + threadIdx.x;
  if (i < C) upd[i] = -1;
}

// ---- virtual-prototype update ----
__global__ void k_vp(const float* __restrict__ queue, const float* __restrict__ emb,
                     const int* __restrict__ labels, float* __restrict__ newrow,
                     int* __restrict__ upd){
  int b = blockIdx.x, t = threadIdx.x;
  int lab = labels[b];
  const float* q = queue + (size_t)lab * D_DIM;
  float q0=q[t], q1=q[t+256];
  float e0=emb[b*D_DIM+t], e1=emb[b*D_DIM+256+t];
  __shared__ float red[256];
  __shared__ int win;
  red[t] = q0*e0 + q1*e1;
  __syncthreads();
  for (int o=128;o>0;o>>=1){ if(t<o) red[t]+=red[t+o]; __syncthreads(); }
  float drift = red[0];
  float fac = drift / (1.0f + fabsf(drift));
  float v0 = fac*q0 + (1.0f-fac)*e0;
  float v1 = fac*q1 + (1.0f-fac)*e1;
  __syncthreads();
  if (t==0) win = 1;
  red[t] = v0*v0 + v1*v1;
  __syncthreads();
  for (int o=128;o>0;o>>=1){ if(t<o) red[t]+=red[t+o]; __syncthreads(); }
  float inv = 1.0f / fmaxf(sqrtf(red[0]), 1e-12f);
  newrow[b*D_DIM+t]     = v0*inv;
  newrow[b*D_DIM+256+t] = v1*inv;
  if (t > b && labels[t] == lab) win = 0;
  __syncthreads();
  if (t==0 && win) upd[lab] = b;
}

// ---- fused double-GEMM: LDS-staged (global_load_lds + XOR swizzle) ----
// wg = 32 classes; 4 waves; wave w owns emb rows [w*64, w*64+64) x 32 cols x 2 mats.
// LDS per buffer: W[32][32]f32 (4KB) + Q[32][32]f32 (4KB); double-buffered = 16KB.
// Swizzle: 16B granule g of row r stored at physical slot g^(r&7); the per-lane
// GLOBAL source is pre-swizzled so the LDS dest stays linear (both-sides rule).
__global__ __launch_bounds__(256,3) void k_main(
    const float* __restrict__ W, const float* __restrict__ Q,
    const short* __restrict__ embA, const float* __restrict__ newrow,
    const int* __restrict__ upd, const int* __restrict__ labels,
    float* __restrict__ partials, float* __restrict__ posval,
    int C, int nwg)
{
  __shared__ __align__(16) char ldsb[2*8192];
  const int wg   = blockIdx.x;
  const int tid  = threadIdx.x;
  const int wave = tid >> 6;
  const int lane = tid & 63;
  const int lcol = lane & 15;
  const int lkg  = lane >> 4;
  const int c0 = wg * NT;
  const int m0 = wave * 64;

  // staging assignment: chunk = wave*2+i (8 chunks of 1KB); chunk c: mat=c>>2,
  // rows (c&3)*8 + (lane>>3), dest granule = lane&7, source granule = (lane&7)^(lane>>3)
  const char* ssrc[2];
  int sdst[2];
#pragma unroll
  for (int i=0;i<2;i++){
    int ch  = wave*2 + i;
    int mat = ch >> 2;
    int r   = (ch&3)*8 + (lane>>3);
    int gs  = (lane&7) ^ (lane>>3);
    int cls = c0 + r; if (cls >= C) cls = C-1;
    const float* rowp;
    if (mat == 0) rowp = W + (size_t)cls * D_DIM;
    else {
      int u = upd[cls];
      rowp = (u >= 0) ? (newrow + (size_t)u * D_DIM) : (Q + (size_t)cls * D_DIM);
    }
    ssrc[i] = (const char*)(rowp + gs*4);
    sdst[i] = ch * 1024;                 // wave-uniform LDS base
  }

  const short8* Af = reinterpret_cast<const short8*>(embA);
  const f32x4 vzero = {0.f,0.f,0.f,0.f};
  f32x4 accW[4][2], accQ[4][2];
#pragma unroll
  for (int i=0;i<4;i++)
#pragma unroll
    for (int j=0;j<2;j++){ accW[i][j]=vzero; accQ[i][j]=vzero; }
  float wss[2] = {0.f,0.f};
  float qss[2] = {0.f,0.f};

  // prologue: stage ks=0 into buf0; prefetch af for ks=0
  short8 afc[4], afn[4];
#pragma unroll
  for (int i=0;i<2;i++) gload16(ssrc[i], ldsb + sdst[i]);
#pragma unroll
  for (int rb=0;rb<4;rb++) afc[rb] = Af[(wave*4 + rb)*64 + lane];
  __syncthreads();

  for (int ks=0; ks<KSTEPS; ++ks){
    const int cur = ks & 1;
    if (ks+1 < KSTEPS){
#pragma unroll
      for (int i=0;i<2;i++)
        gload16(ssrc[i] + (ks+1)*128, ldsb + (cur^1)*8192 + sdst[i]);
#pragma unroll
      for (int rb=0;rb<4;rb++) afn[rb] = Af[((ks+1)*16 + wave*4 + rb)*64 + lane];
    }
    const char* bb = ldsb + cur*8192;
#pragma unroll
    for (int cb=0;cb<2;cb++){
      const int row = cb*16 + lcol;
      const int s   = row & 7;
      const int g0  = lkg*2;
      const f32x4 w0 = *(const f32x4*)(bb + row*128 + (((g0  )^s)*16));
      const f32x4 w1 = *(const f32x4*)(bb + row*128 + (((g0+1)^s)*16));
      const f32x4 z0 = *(const f32x4*)(bb + 4096 + row*128 + (((g0  )^s)*16));
      const f32x4 z1 = *(const f32x4*)(bb + 4096 + row*128 + (((g0+1)^s)*16));
      wss[cb] += w0[0]*w0[0]+w0[1]*w0[1]+w0[2]*w0[2]+w0[3]*w0[3]
               + w1[0]*w1[0]+w1[1]*w1[1]+w1[2]*w1[2]+w1[3]*w1[3];
      qss[cb] += z0[0]*z0[0]+z0[1]*z0[1]+z0[2]*z0[2]+z0[3]*z0[3]
               + z1[0]*z1[0]+z1[1]*z1[1]+z1[2]*z1[2]+z1[3]*z1[3];
      short8 bw, bq;
#pragma unroll
      for (int j=0;j<4;j++){
        bw[j] = f2bf(w0[j]); bw[j+4] = f2bf(w1[j]);
        bq[j] = f2bf(z0[j]); bq[j+4] = f2bf(z1[j]);
      }
#pragma unroll
      for (int rb=0;rb<4;rb++)
        accW[rb][cb] = __builtin_amdgcn_mfma_f32_16x16x32_bf16(afc[rb], bw, accW[rb][cb], 0, 0, 0);
#pragma unroll
      for (int rb=0;rb<4;rb++)
        accQ[rb][cb] = __builtin_amdgcn_mfma_f32_16x16x32_bf16(afc[rb], bq, accQ[rb][cb], 0, 0, 0);
    }
    __syncthreads();
#pragma unroll
    for (int rb=0;rb<4;rb++) afc[rb] = afn[rb];
  }

  // column norms
  float winv[2], qinv[2];
#pragma unroll
  for (int cb=0;cb<2;cb++){
    float w = wss[cb]; w += __shfl_xor(w, 16); w += __shfl_xor(w, 32);
    float q = qss[cb]; q += __shfl_xor(q, 16); q += __shfl_xor(q, 32);
    winv[cb] = 1.0f / fmaxf(sqrtf(w), 1e-5f);
    qinv[cb] = 1.0f / fmaxf(sqrtf(q), 1e-12f);
  }

  // epilogue
#pragma unroll
  for (int rb=0;rb<4;rb++){
#pragma unroll
    for (int r=0;r<4;r++){
      const int m = m0 + rb*16 + lkg*4 + r;
      const int lab = labels[m];
      float nw = 0.f, nq = 0.f;
#pragma unroll
      for (int cb=0;cb<2;cb++){
        int c = c0 + cb*16 + lcol;
        if (c < C){
          float cw = accW[rb][cb][r] * winv[cb];
          cw = fminf(fmaxf(cw, -1.0f + 1e-7f), 1.0f - 1e-7f);
          float cq = accQ[rb][cb][r] * qinv[cb];
          if (c == lab){
            float sw  = sqrtf(fminf(fmaxf(1.0f - cw*cw, 0.0f), 1.0f));
            float phw = cw*COS_M - sw*SIN_M;
            posval[m] = __expf(-S_SCALE*phw);
            float vq  = 0.3f * cq;
            float sq  = sqrtf(fminf(fmaxf(1.0f - vq*vq, 0.0f), 1.0f));
            float phq = vq*COS_M - sq*SIN_M;
            posval[NROWS + m] = __expf(-S_SCALE*phq);
          } else {
            nw += __expf(S_SCALE*cw);
            nq += __expf(S_SCALE*cq);
          }
        }
      }
#pragma unroll
      for (int msk=1; msk<16; msk<<=1){
        nw += __shfl_xor(nw, msk);
        nq += __shfl_xor(nq, msk);
      }
      if (lcol == 0){
        partials[(size_t)wg*512 + m]       = nw;   // wg-major: line-dense writes
        partials[(size_t)wg*512 + 256 + m] = nq;
      }
    }
  }
}

// ---- reduce partials per row, loss per row ----
__global__ void k_red(const float* __restrict__ partials, const float* __restrict__ posval,
                      float* __restrict__ lossv, int nwg){
  int n = blockIdx.x, t = threadIdx.x;            // 512 blocks x 256 threads
  float s = 0.f;
  for (int i=t; i<nwg; i+=256) s += partials[(size_t)i*512 + n];
  __shared__ float red[256];
  red[t] = s; __syncthreads();
  for (int o=128;o>0;o>>=1){ if(t<o) red[t]+=red[t+o]; __syncthreads(); }
  if (t==0) lossv[n] = logf(1.0f + red[0] * posval[n]);
}

__global__ void k_fin(const float* __restrict__ lossv, const int* __restrict__ epoch,
                      float* __restrict__ out){
  int t = threadIdx.x;
  int N = (epoch[0] + 1 >= 4) ? 2*NROWS : NROWS;
  float v = (t < N) ? lossv[t] : 0.f;
  __shared__ float red[512];
  red[t] = v; __syncthreads();
  for (int o=256;o>0;o>>=1){ if(t<o) red[t]+=red[t+o]; __syncthreads(); }
  if (t==0) out[0] = red[0] / (float)N;
}

extern "C" void kernel_launch(void* const* d_in, const int* in_sizes, int n_in,
                              void* d_out, int out_size, void* d_ws, size_t ws_size,
                              hipStream_t stream)
{
  const float* x      = (const float*)d_in[0];
  const int*   labels = (const int*)d_in[1];
  const float* W      = (const float*)d_in[2];
  const float* Q      = (const float*)d_in[3];
  const int*   epoch  = (const int*)d_in[4];
  float* out = (float*)d_out;
  const int C   = in_sizes[2] / D_DIM;            // 100000
  const int nwg = (C + NT - 1) / NT;              // 3125

  char* ws = (char*)d_ws;
  float* emb      = (float*)(ws + 0);             // 512 KB
  short* embA     = (short*)(ws + 524288);        // 256 KB
  float* newrow   = (float*)(ws + 786432);        // 512 KB
  int*   upd      = (int*)  (ws + 1310720);       // 400 KB
  float* posval   = (float*)(ws + 1712128);       // 2 KB
  float* lossv    = (float*)(ws + 1714176);       // 2 KB
  float* partials = (float*)(ws + 1716224);       // 512*nwg*4 B (~6.4 MB)

  hipLaunchKernelGGL(k_emb,  dim3(NROWS),       dim3(256), 0, stream, x, emb, embA);
  hipLaunchKernelGGL(k_init, dim3((C+255)/256), dim3(256), 0, stream, upd, C);
  hipLaunchKernelGGL(k_vp,   dim3(NROWS),       dim3(256), 0, stream, Q, emb, labels, newrow, upd);
  hipLaunchKernelGGL(k_main, dim3(nwg),         dim3(256), 0, stream,
                     W, Q, embA, newrow, upd, labels, partials, posval, C, nwg);
  hipLaunchKernelGGL(k_red,  dim3(2*NROWS),     dim3(256), 0, stream, partials, posval, lossv, nwg);
  hipLaunchKernelGGL(k_fin,  dim3(1),           dim3(512), 0, stream, lossv, epoch, out);
}

// Round 3
// 165.809 us; speedup vs baseline: 2.4373x; 1.0641x over previous
//
#include <hip/hip_runtime.h>
#include <hip/hip_bf16.h>

#define D_DIM 512
#define NROWS 256
#define NT 32
#define KSTEPS 16
#define S_SCALE 64.0f
#define COS_M 0.9210609940028851f
#define SIN_M 0.3894183423086505f

typedef short short8 __attribute__((ext_vector_type(8)));
typedef float f32x4 __attribute__((ext_vector_type(4)));

typedef const __attribute__((address_space(1))) void* gas1_t;
typedef __attribute__((address_space(3))) void* las3_t;

static __device__ __forceinline__ void gload16(const void* g, void* l){
  __builtin_amdgcn_global_load_lds((gas1_t)g, (las3_t)l, 16, 0, 0);
}

static __device__ __forceinline__ short f2bf(float f){
  __hip_bfloat16 h = __float2bfloat16(f);
  return __builtin_bit_cast(short, h);
}

// ---- emb = l2norm(x, 1e-5); also pack A-fragments (bf16, fragment-major) ----
__global__ void k_emb(const float* __restrict__ x, float* __restrict__ emb,
                      short* __restrict__ embA){
  int b = blockIdx.x, t = threadIdx.x;            // 256 blocks x 256 threads
  float v0 = x[b*D_DIM + t];
  float v1 = x[b*D_DIM + 256 + t];
  __shared__ float red[256];
  red[t] = v0*v0 + v1*v1;
  __syncthreads();
  for (int o=128;o>0;o>>=1){ if(t<o) red[t]+=red[t+o]; __syncthreads(); }
  float inv = 1.0f / fmaxf(sqrtf(red[0]), 1e-5f);
  float e0 = v0*inv, e1 = v1*inv;
  emb[b*D_DIM + t]       = e0;
  emb[b*D_DIM + 256 + t] = e1;
  int rb = b >> 4;
  {
    int d=t; int ks=d>>5, kg=(d>>3)&3, j=d&7;
    int lane=(kg<<4)|(b&15);
    embA[((ks*16+rb)*64+lane)*8+j] = f2bf(e0);
  }
  {
    int d=t+256; int ks=d>>5, kg=(d>>3)&3, j=d&7;
    int lane=(kg<<4)|(b&15);
    embA[((ks*16+rb)*64+lane)*8+j] = f2bf(e1);
  }
}

__global__ void k_init(int* __restrict__ upd, int C){
  int i = blockIdx.x*256 + threadIdx.x;
  if (i < C) upd[i] = -1;
}

// ---- virtual-prototype update ----
__global__ void k_vp(const float* __restrict__ queue, const float* __restrict__ emb,
                     const int* __restrict__ labels, float* __restrict__ newrow,
                     int* __restrict__ upd){
  int b = blockIdx.x, t = threadIdx.x;
  int lab = labels[b];
  const float* q = queue + (size_t)lab * D_DIM;
  float q0=q[t], q1=q[t+256];
  float e0=emb[b*D_DIM+t], e1=emb[b*D_DIM+256+t];
  __shared__ float red[256];
  __shared__ int win;
  red[t] = q0*e0 + q1*e1;
  __syncthreads();
  for (int o=128;o>0;o>>=1){ if(t<o) red[t]+=red[t+o]; __syncthreads(); }
  float drift = red[0];
  float fac = drift / (1.0f + fabsf(drift));
  float v0 = fac*q0 + (1.0f-fac)*e0;
  float v1 = fac*q1 + (1.0f-fac)*e1;
  __syncthreads();
  if (t==0) win = 1;
  red[t] = v0*v0 + v1*v1;
  __syncthreads();
  for (int o=128;o>0;o>>=1){ if(t<o) red[t]+=red[t+o]; __syncthreads(); }
  float inv = 1.0f / fmaxf(sqrtf(red[0]), 1e-12f);
  newrow[b*D_DIM+t]     = v0*inv;
  newrow[b*D_DIM+256+t] = v1*inv;
  if (t > b && labels[t] == lab) win = 0;
  __syncthreads();
  if (t==0 && win) upd[lab] = b;
}

// ---- fused double-GEMM: 4-deep LDS ring, counted vmcnt, raw barriers ----
// wg = 32 classes; 4 waves x 64 emb-rows each. Ring: 4 bufs x (W 4KB + Q 4KB).
// Issue order per iter (pinned by sched_barrier): af(ks+1) x4, stage(ks+3) x2.
// Steady-state wait vmcnt(2): forces stage(ks+1)+af(ks) complete, leaves
// stage(ks+3) in flight. Row norms via Gram MFMA (diag extracted in epilogue).
__global__ __launch_bounds__(256,3) void k_main(
    const float* __restrict__ W, const float* __restrict__ Q,
    const short* __restrict__ embA, const float* __restrict__ newrow,
    const int* __restrict__ upd, const int* __restrict__ labels,
    float* __restrict__ partials, float* __restrict__ posval,
    int C, int nwg)
{
  __shared__ __align__(16) char ldsb[4*8192];
  const int wg   = blockIdx.x;
  const int tid  = threadIdx.x;
  const int wave = tid >> 6;
  const int lane = tid & 63;
  const int lcol = lane & 15;
  const int lkg  = lane >> 4;
  const int c0 = wg * NT;
  const int m0 = wave * 64;

  // staging: chunk = wave*2+i; chunk c: mat=c>>2, row (c&3)*8+(lane>>3),
  // dest granule lane&7 (linear), source granule (lane&7)^(lane>>3) (pre-swizzled)
  const char* ssrc[2];
  int sdst[2];
#pragma unroll
  for (int i=0;i<2;i++){
    int ch  = wave*2 + i;
    int mat = ch >> 2;
    int r   = (ch&3)*8 + (lane>>3);
    int gs  = (lane&7) ^ (lane>>3);
    int cls = c0 + r; if (cls >= C) cls = C-1;
    const float* rowp;
    if (mat == 0) rowp = W + (size_t)cls * D_DIM;
    else {
      int u = upd[cls];
      rowp = (u >= 0) ? (newrow + (size_t)u * D_DIM) : (Q + (size_t)cls * D_DIM);
    }
    ssrc[i] = (const char*)(rowp + gs*4);
    sdst[i] = ch * 1024;
  }
  __builtin_amdgcn_sched_barrier(0);

  const short8* Af = reinterpret_cast<const short8*>(embA);
  const f32x4 vzero = {0.f,0.f,0.f,0.f};
  f32x4 accW[4][2], accQ[4][2], accNW[2], accNQ[2];
#pragma unroll
  for (int i=0;i<4;i++)
#pragma unroll
    for (int j=0;j<2;j++){ accW[i][j]=vzero; accQ[i][j]=vzero; }
  accNW[0]=vzero; accNW[1]=vzero; accNQ[0]=vzero; accNQ[1]=vzero;

  short8 afc[4], afn[4];
  // prologue: af(0), then stage(0),stage(1),stage(2) — order pinned
#pragma unroll
  for (int rb=0;rb<4;rb++) afc[rb] = Af[(wave*4 + rb)*64 + lane];
  __builtin_amdgcn_sched_barrier(0);
#pragma unroll
  for (int t=0;t<3;t++){
#pragma unroll
    for (int i=0;i<2;i++)
      gload16(ssrc[i] + t*128, ldsb + t*8192 + sdst[i]);
    __builtin_amdgcn_sched_barrier(0);
  }

#pragma unroll
  for (int ks=0; ks<KSTEPS; ++ks){
    if (ks == 0)            asm volatile("s_waitcnt vmcnt(4)" ::: "memory");
    else if (ks < KSTEPS-2) asm volatile("s_waitcnt vmcnt(2)" ::: "memory");
    else                    asm volatile("s_waitcnt vmcnt(0)" ::: "memory");
    __builtin_amdgcn_s_barrier();
    __builtin_amdgcn_sched_barrier(0);
    if (ks+1 < KSTEPS){
#pragma unroll
      for (int rb=0;rb<4;rb++) afn[rb] = Af[((ks+1)*16 + wave*4 + rb)*64 + lane];
    }
    __builtin_amdgcn_sched_barrier(0);
    if (ks+3 < KSTEPS){
#pragma unroll
      for (int i=0;i<2;i++)
        gload16(ssrc[i] + (ks+3)*128, ldsb + ((ks+3)&3)*8192 + sdst[i]);
    }
    __builtin_amdgcn_sched_barrier(0);

    const char* bb = ldsb + (ks&3)*8192;
#pragma unroll
    for (int cb=0;cb<2;cb++){
      const int row = cb*16 + lcol;
      const int s   = row & 7;
      const int g0  = lkg*2;
      const f32x4 w0 = *(const f32x4*)(bb + row*128 + (((g0  )^s)*16));
      const f32x4 w1 = *(const f32x4*)(bb + row*128 + (((g0+1)^s)*16));
      const f32x4 z0 = *(const f32x4*)(bb + 4096 + row*128 + (((g0  )^s)*16));
      const f32x4 z1 = *(const f32x4*)(bb + 4096 + row*128 + (((g0+1)^s)*16));
      short8 bw, bq;
#pragma unroll
      for (int j=0;j<4;j++){
        bw[j] = f2bf(w0[j]); bw[j+4] = f2bf(w1[j]);
        bq[j] = f2bf(z0[j]); bq[j+4] = f2bf(z1[j]);
      }
      // row norms on the matrix pipe: Gram(b,b) accumulates sum_k b[r][k]b[c][k]
      accNW[cb] = __builtin_amdgcn_mfma_f32_16x16x32_bf16(bw, bw, accNW[cb], 0, 0, 0);
      accNQ[cb] = __builtin_amdgcn_mfma_f32_16x16x32_bf16(bq, bq, accNQ[cb], 0, 0, 0);
#pragma unroll
      for (int rb=0;rb<4;rb++)
        accW[rb][cb] = __builtin_amdgcn_mfma_f32_16x16x32_bf16(afc[rb], bw, accW[rb][cb], 0, 0, 0);
#pragma unroll
      for (int rb=0;rb<4;rb++)
        accQ[rb][cb] = __builtin_amdgcn_mfma_f32_16x16x32_bf16(afc[rb], bq, accQ[rb][cb], 0, 0, 0);
    }
#pragma unroll
    for (int rb=0;rb<4;rb++) afc[rb] = afn[rb];  // renamed away by full unroll
  }

  // column norms from Gram diagonals: diag col c lives on lane ((c>>2)<<4)|c, reg c&3
  float winv[2], qinv[2];
#pragma unroll
  for (int cb=0;cb<2;cb++){
    int rsel = lcol & 3;
    float vw = rsel==0?accNW[cb][0]:rsel==1?accNW[cb][1]:rsel==2?accNW[cb][2]:accNW[cb][3];
    float vq = rsel==0?accNQ[cb][0]:rsel==1?accNQ[cb][1]:rsel==2?accNQ[cb][2]:accNQ[cb][3];
    int src = ((lcol>>2)<<4) | lcol;
    float ssW = __shfl(vw, src);
    float ssQ = __shfl(vq, src);
    winv[cb] = 1.0f / fmaxf(sqrtf(ssW), 1e-5f);
    qinv[cb] = 1.0f / fmaxf(sqrtf(ssQ), 1e-12f);
  }

  // epilogue
#pragma unroll
  for (int rb=0;rb<4;rb++){
#pragma unroll
    for (int r=0;r<4;r++){
      const int m = m0 + rb*16 + lkg*4 + r;
      const int lab = labels[m];
      float nw = 0.f, nq = 0.f;
#pragma unroll
      for (int cb=0;cb<2;cb++){
        int c = c0 + cb*16 + lcol;
        if (c < C){
          float cw = accW[rb][cb][r] * winv[cb];
          cw = fminf(fmaxf(cw, -1.0f + 1e-7f), 1.0f - 1e-7f);
          float cq = accQ[rb][cb][r] * qinv[cb];
          if (c == lab){
            float sw  = sqrtf(fminf(fmaxf(1.0f - cw*cw, 0.0f), 1.0f));
            float phw = cw*COS_M - sw*SIN_M;
            posval[m] = __expf(-S_SCALE*phw);
            float vq  = 0.3f * cq;
            float sq  = sqrtf(fminf(fmaxf(1.0f - vq*vq, 0.0f), 1.0f));
            float phq = vq*COS_M - sq*SIN_M;
            posval[NROWS + m] = __expf(-S_SCALE*phq);
          } else {
            nw += __expf(S_SCALE*cw);
            nq += __expf(S_SCALE*cq);
          }
        }
      }
#pragma unroll
      for (int msk=1; msk<16; msk<<=1){
        nw += __shfl_xor(nw, msk);
        nq += __shfl_xor(nq, msk);
      }
      if (lcol == 0){
        partials[(size_t)wg*512 + m]       = nw;
        partials[(size_t)wg*512 + 256 + m] = nq;
      }
    }
  }
}

// ---- reduce partials per row, loss per row ----
__global__ void k_red(const float* __restrict__ partials, const float* __restrict__ posval,
                      float* __restrict__ lossv, int nwg){
  int n = blockIdx.x, t = threadIdx.x;
  float s = 0.f;
  for (int i=t; i<nwg; i+=256) s += partials[(size_t)i*512 + n];
  __shared__ float red[256];
  red[t] = s; __syncthreads();
  for (int o=128;o>0;o>>=1){ if(t<o) red[t]+=red[t+o]; __syncthreads(); }
  if (t==0) lossv[n] = logf(1.0f + red[0] * posval[n]);
}

__global__ void k_fin(const float* __restrict__ lossv, const int* __restrict__ epoch,
                      float* __restrict__ out){
  int t = threadIdx.x;
  int N = (epoch[0] + 1 >= 4) ? 2*NROWS : NROWS;
  float v = (t < N) ? lossv[t] : 0.f;
  __shared__ float red[512];
  red[t] = v; __syncthreads();
  for (int o=256;o>0;o>>=1){ if(t<o) red[t]+=red[t+o]; __syncthreads(); }
  if (t==0) out[0] = red[0] / (float)N;
}

extern "C" void kernel_launch(void* const* d_in, const int* in_sizes, int n_in,
                              void* d_out, int out_size, void* d_ws, size_t ws_size,
                              hipStream_t stream)
{
  const float* x      = (const float*)d_in[0];
  const int*   labels = (const int*)d_in[1];
  const float* W      = (const float*)d_in[2];
  const float* Q      = (const float*)d_in[3];
  const int*   epoch  = (const int*)d_in[4];
  float* out = (float*)d_out;
  const int C   = in_sizes[2] / D_DIM;            // 100000
  const int nwg = (C + NT - 1) / NT;              // 3125

  char* ws = (char*)d_ws;
  float* emb      = (float*)(ws + 0);             // 512 KB
  short* embA     = (short*)(ws + 524288);        // 256 KB
  float* newrow   = (float*)(ws + 786432);        // 512 KB
  int*   upd      = (int*)  (ws + 1310720);       // 400 KB
  float* posval   = (float*)(ws + 1712128);       // 2 KB
  float* lossv    = (float*)(ws + 1714176);       // 2 KB
  float* partials = (float*)(ws + 1716224);       // 512*nwg*4 B (~6.4 MB)

  hipLaunchKernelGGL(k_emb,  dim3(NROWS),       dim3(256), 0, stream, x, emb, embA);
  hipLaunchKernelGGL(k_init, dim3((C+255)/256), dim3(256), 0, stream, upd, C);
  hipLaunchKernelGGL(k_vp,   dim3(NROWS),       dim3(256), 0, stream, Q, emb, labels, newrow, upd);
  hipLaunchKernelGGL(k_main, dim3(nwg),         dim3(256), 0, stream,
                     W, Q, embA, newrow, upd, labels, partials, posval, C, nwg);
  hipLaunchKernelGGL(k_red,  dim3(2*NROWS),     dim3(256), 0, stream, partials, posval, lossv, nwg);
  hipLaunchKernelGGL(k_fin,  dim3(1),           dim3(512), 0, stream, lossv, epoch, out);
}